// Round 3
// baseline (325.205 us; speedup 1.0000x reference)
//
#include <hip/hip_runtime.h>
#include <hip/hip_bf16.h>
#include <math.h>

// Problem constants (fixed by the reference)
#define B_SZ   4096
#define D      64
#define RPB    8192                 // rows per branch = 2*B
#define NCHUNK 16                   // column chunks (blockIdx.y)
#define TPC    4                    // 128-col tiles per chunk
#define NPART  32                   // partials per row = NCHUNK * 2 (wn halves)
#define LN2    0.69314718055994531f
#define PRESCALE 2.6857914f         // sqrt(5 * log2(e)); X pre-scaled so Gram = base-2 logits

typedef __attribute__((ext_vector_type(8))) short  bf16x8;
typedef __attribute__((ext_vector_type(4))) float  f32x4;

__device__ __forceinline__ float fexp2(float x) { return __builtin_amdgcn_exp2f(x); }

// ws layout:
//   Xbf  : 2*8192*64 bf16  = 2 MB   (pre-scaled by PRESCALE)
//   dots : 8192 float      = 32 KB  (v1_i . v2_i, unscaled fp32)
//   P    : 16384*32 float2 = 4 MB   (per-row per-(chunk,wn) (m,s), base-2; user m=0)

// ---------------------------------------------------------------------------
__global__ __launch_bounds__(256) void gather_kernel(
    const int* __restrict__ u_idx, const int* __restrict__ i_idx,
    const float* __restrict__ u1e, const float* __restrict__ i1e,
    const float* __restrict__ u2e, const float* __restrict__ i2e,
    __hip_bfloat16* __restrict__ Xbf, float* __restrict__ dots)
{
    const int tid  = threadIdx.x;
    const int wave = tid >> 6, lane = tid & 63;
    const int g      = blockIdx.x * 4 + wave;   // 0..8191
    const int branch = g >> 12;
    const int i      = g & (B_SZ - 1);
    const int idx    = (branch == 0) ? u_idx[i] : i_idx[i];
    const float* s1  = (branch == 0) ? u1e : i1e;
    const float* s2  = (branch == 0) ? u2e : i2e;

    float v1 = s1[(size_t)idx * D + lane];
    float v2 = s2[(size_t)idx * D + lane];
    if (branch == 0) {
        float a = v1 * v1, b = v2 * v2;
        #pragma unroll
        for (int o = 32; o > 0; o >>= 1) {
            a += __shfl_xor(a, o, 64);
            b += __shfl_xor(b, o, 64);
        }
        v1 *= rsqrtf(a);
        v2 *= rsqrtf(b);
    }
    float p = v1 * v2;
    #pragma unroll
    for (int o = 32; o > 0; o >>= 1) p += __shfl_xor(p, o, 64);
    if (lane == 0) dots[g] = p;

    const size_t row1 = (size_t)branch * RPB + i;
    Xbf[row1 * D + lane]          = __float2bfloat16(v1 * PRESCALE);
    Xbf[(row1 + B_SZ) * D + lane] = __float2bfloat16(v2 * PRESCALE);
}

// ---------------------------------------------------------------------------
// Barrier-free MFMA Gram + per-lane online logsumexp (base-2).
// X per branch is 1 MB -> L2-resident; MFMA fragments loaded directly from
// global. No LDS, no __syncthreads. Both branches fused via grid z.
// R3: 2x finer grid (NCHUNK=16, 2048 blocks -> 8 waves/SIMD schedulable) and
// software prefetch of tile t+1's B fragments under tile t's exp2 epilogue,
// so the per-tile vmcnt stall overlaps ~700 cycles of VALU work.
// Block: 4 waves, each owns a 64x64 C subtile (4x4 MFMA 16x16x32, K=64).
// IS_USER=1: logits bounded (|y|<=7.3) -> no max tracking, plain exp2-sum.
template<int IS_USER>
__device__ __forceinline__ void gram_body(
    const __hip_bfloat16* __restrict__ Xb, float2* __restrict__ P)
{
    const int tid   = threadIdx.x;
    const int bx    = blockIdx.x;
    const int chunk = blockIdx.y;
    const int r0    = bx * 128;

    const int wave = tid >> 6, lane = tid & 63;
    const int wm = wave >> 1, wn = wave & 1;
    const int quad = lane >> 4, tx = lane & 15;

    // A fragments hoisted to registers, straight from global (K=64 fits).
    bf16x8 afr[4][2];
    const __hip_bfloat16* Ap = Xb + (size_t)(r0 + wm * 64 + tx) * D + quad * 8;
    #pragma unroll
    for (int mt = 0; mt < 4; ++mt)
        #pragma unroll
        for (int ks = 0; ks < 2; ++ks)
            afr[mt][ks] = *(const bf16x8*)(Ap + mt * 16 * D + ks * 32);

    float m_run[16], s_run[16];
    #pragma unroll
    for (int r = 0; r < 16; ++r) { m_run[r] = -INFINITY; s_run[r] = 0.f; }

    const int lrq  = wm * 64 + quad * 4;   // + mt*16 + rr = block-local row
    const int lcol = wn * 64 + tx;         // + nt*16      = block-local col

    const __hip_bfloat16* Bbase =
        Xb + (size_t)(chunk * TPC * 128 + wn * 64 + tx) * D + quad * 8;

    // Prologue: load tile 0's B fragments.
    bf16x8 b0[4], b1[4];
    #pragma unroll
    for (int nt = 0; nt < 4; ++nt) {
        b0[nt] = *(const bf16x8*)(Bbase + nt * 16 * D);
        b1[nt] = *(const bf16x8*)(Bbase + nt * 16 * D + 32);
    }

    #pragma unroll 1
    for (int t = 0; t < TPC; ++t) {
        const int ct = chunk * TPC + t;

        // Prefetch tile t+1's fragments; vmcnt-wait lands after the epilogue.
        bf16x8 n0[4], n1[4];
        if (t + 1 < TPC) {
            const __hip_bfloat16* Np = Bbase + (size_t)(t + 1) * 128 * D;
            #pragma unroll
            for (int nt = 0; nt < 4; ++nt) {
                n0[nt] = *(const bf16x8*)(Np + nt * 16 * D);
                n1[nt] = *(const bf16x8*)(Np + nt * 16 * D + 32);
            }
        }

        f32x4 acc[4][4];
        const f32x4 z = {0.f, 0.f, 0.f, 0.f};
        #pragma unroll
        for (int nt = 0; nt < 4; ++nt)
            #pragma unroll
            for (int mt = 0; mt < 4; ++mt)
                acc[mt][nt] = __builtin_amdgcn_mfma_f32_16x16x32_bf16(afr[mt][0], b0[nt], z, 0, 0, 0);
        #pragma unroll
        for (int nt = 0; nt < 4; ++nt)
            #pragma unroll
            for (int mt = 0; mt < 4; ++mt)
                acc[mt][nt] = __builtin_amdgcn_mfma_f32_16x16x32_bf16(afr[mt][1], b1[nt], acc[mt][nt], 0, 0, 0);

        const bool diag = (ct == bx);
        #pragma unroll
        for (int mt = 0; mt < 4; ++mt) {
            #pragma unroll
            for (int rr = 0; rr < 4; ++rr) {
                float y0 = acc[mt][0][rr], y1 = acc[mt][1][rr],
                      y2 = acc[mt][2][rr], y3 = acc[mt][3][rr];
                if (diag) {                  // acc already = base-2 logits (pre-scaled X)
                    const int dr = lrq + mt * 16 + rr - lcol;
                    if (dr == 0)  y0 = -INFINITY;
                    if (dr == 16) y1 = -INFINITY;
                    if (dr == 32) y2 = -INFINITY;
                    if (dr == 48) y3 = -INFINITY;
                }
                const int r = mt * 4 + rr;
                if (IS_USER) {
                    s_run[r] += fexp2(y0) + fexp2(y1) + fexp2(y2) + fexp2(y3);
                } else {
                    float mx   = fmaxf(fmaxf(y0, y1), fmaxf(y2, y3));
                    float newm = fmaxf(m_run[r], mx);
                    s_run[r] = s_run[r] * fexp2(m_run[r] - newm)
                             + fexp2(y0 - newm) + fexp2(y1 - newm)
                             + fexp2(y2 - newm) + fexp2(y3 - newm);
                    m_run[r] = newm;
                }
            }
        }

        if (t + 1 < TPC) {
            #pragma unroll
            for (int nt = 0; nt < 4; ++nt) { b0[nt] = n0[nt]; b1[nt] = n1[nt]; }
        }
    }

    // Once per chunk: merge across the 16 tx lanes of THIS wave, write the
    // (row, chunk, wn) partial to its own slot.
    #pragma unroll
    for (int r = 0; r < 16; ++r) {
        float m = IS_USER ? 0.f : m_run[r];
        float s = s_run[r];
        #pragma unroll
        for (int o = 1; o < 16; o <<= 1) {
            if (IS_USER) {
                s += __shfl_xor(s, o, 64);
            } else {
                float om = __shfl_xor(m, o, 64);
                float os = __shfl_xor(s, o, 64);
                float M  = fmaxf(m, om);
                s = s * fexp2(m - M) + os * fexp2(om - M);
                m = M;
            }
        }
        if (tx == 0) {
            const int grow = r0 + wm * 64 + (r >> 2) * 16 + quad * 4 + (r & 3);
            P[(size_t)grow * NPART + chunk * 2 + wn] = make_float2(m, s);
        }
    }
}

__global__ __launch_bounds__(256, 4) void gram_lse_fused(
    const __hip_bfloat16* __restrict__ Xb0, float2* __restrict__ P0)
{
    const int branch = blockIdx.z;              // 0 = user, 1 = item
    const __hip_bfloat16* Xb = Xb0 + (size_t)branch * RPB * D;
    float2* P = P0 + (size_t)branch * RPB * NPART;
    if (branch == 0) gram_body<1>(Xb, P);
    else             gram_body<0>(Xb, P);
}

// ---------------------------------------------------------------------------
// Merge the 32 per-row partials -> lse -> reduce; fold in the positive-pair
// correction from dots[]. 128 blocks; each block covers 128 rows over 16
// iterations (each wave merges 2 rows with a 32-lane online merge).
__global__ __launch_bounds__(256) void merge_kernel(
    const float2* __restrict__ P, const float* __restrict__ dots,
    float* __restrict__ out)
{
    __shared__ float red[4];
    const int tid  = threadIdx.x;
    const int wave = tid >> 6, lane = tid & 63;

    float vsum = 0.f;
    #pragma unroll
    for (int it = 0; it < 16; ++it) {
        const int row = blockIdx.x * 128 + it * 8 + wave * 2 + (lane >> 5);
        const int c   = lane & 31;

        float2 p = P[(size_t)row * NPART + c];
        float m = p.x, s = p.y;
        #pragma unroll
        for (int o = 1; o < 32; o <<= 1) {         // online merge across 32 lanes
            float om = __shfl_xor(m, o, 64);
            float os = __shfl_xor(s, o, 64);
            float M  = fmaxf(m, om);
            s = s * fexp2(m - M) + os * fexp2(om - M);
            m = M;
        }

        if ((lane & 31) == 0)
            vsum += LN2 * (m + log2f(s)) * (1.0f / (float)RPB);   // lse_row / (2B)
    }

    // positive-pair correction: 64 dots per block
    if (tid < 64)
        vsum -= dots[blockIdx.x * 64 + tid] * (5.0f / (float)B_SZ);

    float v = vsum;
    #pragma unroll
    for (int o = 32; o > 0; o >>= 1) v += __shfl_xor(v, o, 64);
    if (lane == 0) red[wave] = v;
    __syncthreads();
    if (tid == 0)
        atomicAdd(out, red[0] + red[1] + red[2] + red[3]);
}

// ---------------------------------------------------------------------------
extern "C" void kernel_launch(void* const* d_in, const int* in_sizes, int n_in,
                              void* d_out, int out_size, void* d_ws, size_t ws_size,
                              hipStream_t stream) {
    const int*   u_idx = (const int*)d_in[0];
    const int*   i_idx = (const int*)d_in[1];
    const float* u1e   = (const float*)d_in[2];
    const float* i1e   = (const float*)d_in[3];
    const float* u2e   = (const float*)d_in[4];
    const float* i2e   = (const float*)d_in[5];
    float* out = (float*)d_out;

    __hip_bfloat16* Xbf = (__hip_bfloat16*)d_ws;                  // 2 MB
    float*  dots = (float*)((char*)d_ws + 2 * RPB * D * 2);       // 32 KB
    float2* P    = (float2*)((char*)dots + RPB * sizeof(float));  // 4 MB

    hipMemsetAsync(out, 0, sizeof(float), stream);

    gather_kernel<<<dim3(2048), dim3(256), 0, stream>>>(
        u_idx, i_idx, u1e, i1e, u2e, i2e, Xbf, dots);
    // both branches in one barrier-free launch: grid z = {user, item}
    gram_lse_fused<<<dim3(64, NCHUNK, 2), dim3(256), 0, stream>>>(Xbf, P);
    merge_kernel<<<dim3(128), dim3(256), 0, stream>>>(P, dots, out);
}

// Round 4
// 206.944 us; speedup vs baseline: 1.5715x; 1.5715x over previous
//
#include <hip/hip_runtime.h>
#include <hip/hip_bf16.h>
#include <math.h>

// Problem constants (fixed by the reference)
#define B_SZ   4096
#define D      64
#define RPB    8192                 // rows per branch = 2*B
#define NCHUNK 16                   // column chunks (blockIdx.y)
#define TPC    4                    // 128-col tiles per chunk
#define NPART  32                   // partials per row = NCHUNK * 2 (wn halves)
#define LN2    0.69314718055994531f
#define PRESCALE 2.6857914f         // sqrt(5 * log2(e)); X pre-scaled so Gram = base-2 logits

typedef __attribute__((ext_vector_type(8))) short  bf16x8;
typedef __attribute__((ext_vector_type(4))) float  f32x4;

__device__ __forceinline__ float fexp2(float x) { return __builtin_amdgcn_exp2f(x); }

// ws layout:
//   Xbf  : 2*8192*64 bf16  = 2 MB   (pre-scaled by PRESCALE)
//   dots : 8192 float      = 32 KB  (v1_i . v2_i, unscaled fp32)
//   P    : 16384*32 float2 = 4 MB   (per-row per-(chunk,wn) (m,s), base-2; user m=0)

// ---------------------------------------------------------------------------
__global__ __launch_bounds__(256) void gather_kernel(
    const int* __restrict__ u_idx, const int* __restrict__ i_idx,
    const float* __restrict__ u1e, const float* __restrict__ i1e,
    const float* __restrict__ u2e, const float* __restrict__ i2e,
    __hip_bfloat16* __restrict__ Xbf, float* __restrict__ dots)
{
    const int tid  = threadIdx.x;
    const int wave = tid >> 6, lane = tid & 63;
    const int g      = blockIdx.x * 4 + wave;   // 0..8191
    const int branch = g >> 12;
    const int i      = g & (B_SZ - 1);
    const int idx    = (branch == 0) ? u_idx[i] : i_idx[i];
    const float* s1  = (branch == 0) ? u1e : i1e;
    const float* s2  = (branch == 0) ? u2e : i2e;

    float v1 = s1[(size_t)idx * D + lane];
    float v2 = s2[(size_t)idx * D + lane];
    if (branch == 0) {
        float a = v1 * v1, b = v2 * v2;
        #pragma unroll
        for (int o = 32; o > 0; o >>= 1) {
            a += __shfl_xor(a, o, 64);
            b += __shfl_xor(b, o, 64);
        }
        v1 *= rsqrtf(a);
        v2 *= rsqrtf(b);
    }
    float p = v1 * v2;
    #pragma unroll
    for (int o = 32; o > 0; o >>= 1) p += __shfl_xor(p, o, 64);
    if (lane == 0) dots[g] = p;

    const size_t row1 = (size_t)branch * RPB + i;
    Xbf[row1 * D + lane]          = __float2bfloat16(v1 * PRESCALE);
    Xbf[(row1 + B_SZ) * D + lane] = __float2bfloat16(v2 * PRESCALE);
}

// ---------------------------------------------------------------------------
// Barrier-free MFMA Gram + per-lane online logsumexp (base-2).
// X per branch is 1 MB -> L2-resident; MFMA fragments loaded directly from
// global. No LDS, no __syncthreads. Both branches fused via grid z.
// R4: prefetch tile t+1's B fragments INTO THE SAME b0/b1 registers right
// after tile t's MFMAs consume them (zero net register cost, unlike R3's
// spilled n0/n1 temps) -> the vmcnt wait lands after the exp2 epilogue.
// launch_bounds(256,3): 168-VGPR cap, verified-safe budget (R3's (256,4)
// forced 64 VGPR + 580 MB of scratch spill traffic).
// Block: 4 waves, each owns a 64x64 C subtile (4x4 MFMA 16x16x32, K=64).
// IS_USER=1: logits bounded (|y|<=7.3) -> no max tracking, plain exp2-sum.
template<int IS_USER>
__device__ __forceinline__ void gram_body(
    const __hip_bfloat16* __restrict__ Xb, float2* __restrict__ P)
{
    const int tid   = threadIdx.x;
    const int bx    = blockIdx.x;
    const int chunk = blockIdx.y;
    const int r0    = bx * 128;

    const int wave = tid >> 6, lane = tid & 63;
    const int wm = wave >> 1, wn = wave & 1;
    const int quad = lane >> 4, tx = lane & 15;

    // A fragments hoisted to registers, straight from global (K=64 fits).
    bf16x8 afr[4][2];
    const __hip_bfloat16* Ap = Xb + (size_t)(r0 + wm * 64 + tx) * D + quad * 8;
    #pragma unroll
    for (int mt = 0; mt < 4; ++mt)
        #pragma unroll
        for (int ks = 0; ks < 2; ++ks)
            afr[mt][ks] = *(const bf16x8*)(Ap + mt * 16 * D + ks * 32);

    float m_run[16], s_run[16];
    #pragma unroll
    for (int r = 0; r < 16; ++r) { m_run[r] = -INFINITY; s_run[r] = 0.f; }

    const int lrq  = wm * 64 + quad * 4;   // + mt*16 + rr = block-local row
    const int lcol = wn * 64 + tx;         // + nt*16      = block-local col

    const __hip_bfloat16* Bbase =
        Xb + (size_t)(chunk * TPC * 128 + wn * 64 + tx) * D + quad * 8;

    // Prologue: load tile 0's B fragments.
    bf16x8 b0[4], b1[4];
    #pragma unroll
    for (int nt = 0; nt < 4; ++nt) {
        b0[nt] = *(const bf16x8*)(Bbase + nt * 16 * D);
        b1[nt] = *(const bf16x8*)(Bbase + nt * 16 * D + 32);
    }

    #pragma unroll 1
    for (int t = 0; t < TPC; ++t) {
        const int ct = chunk * TPC + t;

        f32x4 acc[4][4];
        const f32x4 z = {0.f, 0.f, 0.f, 0.f};
        #pragma unroll
        for (int nt = 0; nt < 4; ++nt)
            #pragma unroll
            for (int mt = 0; mt < 4; ++mt)
                acc[mt][nt] = __builtin_amdgcn_mfma_f32_16x16x32_bf16(afr[mt][0], b0[nt], z, 0, 0, 0);
        #pragma unroll
        for (int nt = 0; nt < 4; ++nt)
            #pragma unroll
            for (int mt = 0; mt < 4; ++mt)
                acc[mt][nt] = __builtin_amdgcn_mfma_f32_16x16x32_bf16(afr[mt][1], b1[nt], acc[mt][nt], 0, 0, 0);

        // Prefetch tile t+1 into the SAME registers (b's are dead after the
        // MFMAs above); the waitcnt lands after the epilogue below.
        if (t + 1 < TPC) {
            const __hip_bfloat16* Np = Bbase + (size_t)(t + 1) * 128 * D;
            #pragma unroll
            for (int nt = 0; nt < 4; ++nt) {
                b0[nt] = *(const bf16x8*)(Np + nt * 16 * D);
                b1[nt] = *(const bf16x8*)(Np + nt * 16 * D + 32);
            }
        }

        const bool diag = (ct == bx);
        #pragma unroll
        for (int mt = 0; mt < 4; ++mt) {
            #pragma unroll
            for (int rr = 0; rr < 4; ++rr) {
                float y0 = acc[mt][0][rr], y1 = acc[mt][1][rr],
                      y2 = acc[mt][2][rr], y3 = acc[mt][3][rr];
                if (diag) {                  // acc already = base-2 logits (pre-scaled X)
                    const int dr = lrq + mt * 16 + rr - lcol;
                    if (dr == 0)  y0 = -INFINITY;
                    if (dr == 16) y1 = -INFINITY;
                    if (dr == 32) y2 = -INFINITY;
                    if (dr == 48) y3 = -INFINITY;
                }
                const int r = mt * 4 + rr;
                if (IS_USER) {
                    s_run[r] += fexp2(y0) + fexp2(y1) + fexp2(y2) + fexp2(y3);
                } else {
                    float mx   = fmaxf(fmaxf(y0, y1), fmaxf(y2, y3));
                    float newm = fmaxf(m_run[r], mx);
                    s_run[r] = s_run[r] * fexp2(m_run[r] - newm)
                             + fexp2(y0 - newm) + fexp2(y1 - newm)
                             + fexp2(y2 - newm) + fexp2(y3 - newm);
                    m_run[r] = newm;
                }
            }
        }
    }

    // Once per chunk: merge across the 16 tx lanes of THIS wave, write the
    // (row, chunk, wn) partial to its own slot.
    #pragma unroll
    for (int r = 0; r < 16; ++r) {
        float m = IS_USER ? 0.f : m_run[r];
        float s = s_run[r];
        #pragma unroll
        for (int o = 1; o < 16; o <<= 1) {
            if (IS_USER) {
                s += __shfl_xor(s, o, 64);
            } else {
                float om = __shfl_xor(m, o, 64);
                float os = __shfl_xor(s, o, 64);
                float M  = fmaxf(m, om);
                s = s * fexp2(m - M) + os * fexp2(om - M);
                m = M;
            }
        }
        if (tx == 0) {
            const int grow = r0 + wm * 64 + (r >> 2) * 16 + quad * 4 + (r & 3);
            P[(size_t)grow * NPART + chunk * 2 + wn] = make_float2(m, s);
        }
    }
}

__global__ __launch_bounds__(256, 3) void gram_lse_fused(
    const __hip_bfloat16* __restrict__ Xb0, float2* __restrict__ P0)
{
    const int branch = blockIdx.z;              // 0 = user, 1 = item
    const __hip_bfloat16* Xb = Xb0 + (size_t)branch * RPB * D;
    float2* P = P0 + (size_t)branch * RPB * NPART;
    if (branch == 0) gram_body<1>(Xb, P);
    else             gram_body<0>(Xb, P);
}

// ---------------------------------------------------------------------------
// Merge the 32 per-row partials -> lse -> reduce; fold in the positive-pair
// correction from dots[]. 128 blocks; each block covers 128 rows over 16
// iterations (each wave merges 2 rows with a 32-lane online merge).
__global__ __launch_bounds__(256) void merge_kernel(
    const float2* __restrict__ P, const float* __restrict__ dots,
    float* __restrict__ out)
{
    __shared__ float red[4];
    const int tid  = threadIdx.x;
    const int wave = tid >> 6, lane = tid & 63;

    float vsum = 0.f;
    #pragma unroll
    for (int it = 0; it < 16; ++it) {
        const int row = blockIdx.x * 128 + it * 8 + wave * 2 + (lane >> 5);
        const int c   = lane & 31;

        float2 p = P[(size_t)row * NPART + c];
        float m = p.x, s = p.y;
        #pragma unroll
        for (int o = 1; o < 32; o <<= 1) {         // online merge across 32 lanes
            float om = __shfl_xor(m, o, 64);
            float os = __shfl_xor(s, o, 64);
            float M  = fmaxf(m, om);
            s = s * fexp2(m - M) + os * fexp2(om - M);
            m = M;
        }

        if ((lane & 31) == 0)
            vsum += LN2 * (m + log2f(s)) * (1.0f / (float)RPB);   // lse_row / (2B)
    }

    // positive-pair correction: 64 dots per block
    if (tid < 64)
        vsum -= dots[blockIdx.x * 64 + tid] * (5.0f / (float)B_SZ);

    float v = vsum;
    #pragma unroll
    for (int o = 32; o > 0; o >>= 1) v += __shfl_xor(v, o, 64);
    if (lane == 0) red[wave] = v;
    __syncthreads();
    if (tid == 0)
        atomicAdd(out, red[0] + red[1] + red[2] + red[3]);
}

// ---------------------------------------------------------------------------
extern "C" void kernel_launch(void* const* d_in, const int* in_sizes, int n_in,
                              void* d_out, int out_size, void* d_ws, size_t ws_size,
                              hipStream_t stream) {
    const int*   u_idx = (const int*)d_in[0];
    const int*   i_idx = (const int*)d_in[1];
    const float* u1e   = (const float*)d_in[2];
    const float* i1e   = (const float*)d_in[3];
    const float* u2e   = (const float*)d_in[4];
    const float* i2e   = (const float*)d_in[5];
    float* out = (float*)d_out;

    __hip_bfloat16* Xbf = (__hip_bfloat16*)d_ws;                  // 2 MB
    float*  dots = (float*)((char*)d_ws + 2 * RPB * D * 2);       // 32 KB
    float2* P    = (float2*)((char*)dots + RPB * sizeof(float));  // 4 MB

    hipMemsetAsync(out, 0, sizeof(float), stream);

    gather_kernel<<<dim3(2048), dim3(256), 0, stream>>>(
        u_idx, i_idx, u1e, i1e, u2e, i2e, Xbf, dots);
    // both branches in one barrier-free launch: grid z = {user, item}
    gram_lse_fused<<<dim3(64, NCHUNK, 2), dim3(256), 0, stream>>>(Xbf, P);
    merge_kernel<<<dim3(128), dim3(256), 0, stream>>>(P, dots, out);
}

// Round 5
// 176.100 us; speedup vs baseline: 1.8467x; 1.1751x over previous
//
#include <hip/hip_runtime.h>
#include <hip/hip_bf16.h>
#include <math.h>

// Problem constants (fixed by the reference)
#define B_SZ   4096
#define D      64
#define RPB    8192                 // rows per branch = 2*B
#define NCHUNK 16                   // column chunks (blockIdx.y)
#define TPC    4                    // 128-col tiles per chunk
#define NPART  32                   // partials per row = NCHUNK * 2 (wn halves)
#define LN2    0.69314718055994531f
#define PRESCALE 2.6857914f         // sqrt(5 * log2(e)); X pre-scaled so Gram = base-2 logits

typedef __attribute__((ext_vector_type(8))) short  bf16x8;
typedef __attribute__((ext_vector_type(4))) float  f32x4;

__device__ __forceinline__ float fexp2(float x) { return __builtin_amdgcn_exp2f(x); }

// ws layout:
//   Xbf  : 2*8192*64 bf16  = 2 MB   (pre-scaled by PRESCALE)
//   dots : 8192 float      = 32 KB  (v1_i . v2_i, unscaled fp32)
//   P    : 16384*32 float2 = 4 MB   (per-row per-(chunk,wn) (m,s), base-2; user m=0)

// ---------------------------------------------------------------------------
__global__ __launch_bounds__(256) void gather_kernel(
    const int* __restrict__ u_idx, const int* __restrict__ i_idx,
    const float* __restrict__ u1e, const float* __restrict__ i1e,
    const float* __restrict__ u2e, const float* __restrict__ i2e,
    __hip_bfloat16* __restrict__ Xbf, float* __restrict__ dots)
{
    const int tid  = threadIdx.x;
    const int wave = tid >> 6, lane = tid & 63;
    const int g      = blockIdx.x * 4 + wave;   // 0..8191
    const int branch = g >> 12;
    const int i      = g & (B_SZ - 1);
    const int idx    = (branch == 0) ? u_idx[i] : i_idx[i];
    const float* s1  = (branch == 0) ? u1e : i1e;
    const float* s2  = (branch == 0) ? u2e : i2e;

    float v1 = s1[(size_t)idx * D + lane];
    float v2 = s2[(size_t)idx * D + lane];
    if (branch == 0) {
        float a = v1 * v1, b = v2 * v2;
        #pragma unroll
        for (int o = 32; o > 0; o >>= 1) {
            a += __shfl_xor(a, o, 64);
            b += __shfl_xor(b, o, 64);
        }
        v1 *= rsqrtf(a);
        v2 *= rsqrtf(b);
    }
    float p = v1 * v2;
    #pragma unroll
    for (int o = 32; o > 0; o >>= 1) p += __shfl_xor(p, o, 64);
    if (lane == 0) dots[g] = p;

    const size_t row1 = (size_t)branch * RPB + i;
    Xbf[row1 * D + lane]          = __float2bfloat16(v1 * PRESCALE);
    Xbf[(row1 + B_SZ) * D + lane] = __float2bfloat16(v2 * PRESCALE);
}

// ---------------------------------------------------------------------------
// Barrier-free MFMA Gram + per-lane online logsumexp (base-2).
// X per branch is 1 MB -> L2-resident; MFMA fragments loaded directly from
// global. No LDS, no __syncthreads. Both branches fused via grid z.
// R5: prefetch tile t+1's B fragments into the same b0/b1 registers after
// tile t's MFMAs consume them; the vmcnt wait lands after the exp2 epilogue.
// __launch_bounds__(256, 2): observed compiler behavior pins arch-VGPR to a
// fixed occupancy target derived from the bound ((256,3)->84, (256,4)->64,
// spilling to honor it). (256,2) targets ~128 VGPR -> the prefetch's ~115
// live arch VGPRs fit WITHOUT spill (R3/R4 spilled 100-580 MB to scratch).
// Block: 4 waves, each owns a 64x64 C subtile (4x4 MFMA 16x16x32, K=64).
// IS_USER=1: logits bounded (|y|<=7.3) -> no max tracking, plain exp2-sum.
template<int IS_USER>
__device__ __forceinline__ void gram_body(
    const __hip_bfloat16* __restrict__ Xb, float2* __restrict__ P)
{
    const int tid   = threadIdx.x;
    const int bx    = blockIdx.x;
    const int chunk = blockIdx.y;
    const int r0    = bx * 128;

    const int wave = tid >> 6, lane = tid & 63;
    const int wm = wave >> 1, wn = wave & 1;
    const int quad = lane >> 4, tx = lane & 15;

    // A fragments hoisted to registers, straight from global (K=64 fits).
    bf16x8 afr[4][2];
    const __hip_bfloat16* Ap = Xb + (size_t)(r0 + wm * 64 + tx) * D + quad * 8;
    #pragma unroll
    for (int mt = 0; mt < 4; ++mt)
        #pragma unroll
        for (int ks = 0; ks < 2; ++ks)
            afr[mt][ks] = *(const bf16x8*)(Ap + mt * 16 * D + ks * 32);

    float m_run[16], s_run[16];
    #pragma unroll
    for (int r = 0; r < 16; ++r) { m_run[r] = -INFINITY; s_run[r] = 0.f; }

    const int lrq  = wm * 64 + quad * 4;   // + mt*16 + rr = block-local row
    const int lcol = wn * 64 + tx;         // + nt*16      = block-local col

    const __hip_bfloat16* Bbase =
        Xb + (size_t)(chunk * TPC * 128 + wn * 64 + tx) * D + quad * 8;

    // Prologue: load tile 0's B fragments.
    bf16x8 b0[4], b1[4];
    #pragma unroll
    for (int nt = 0; nt < 4; ++nt) {
        b0[nt] = *(const bf16x8*)(Bbase + nt * 16 * D);
        b1[nt] = *(const bf16x8*)(Bbase + nt * 16 * D + 32);
    }

    #pragma unroll 1
    for (int t = 0; t < TPC; ++t) {
        const int ct = chunk * TPC + t;

        f32x4 acc[4][4];
        const f32x4 z = {0.f, 0.f, 0.f, 0.f};
        #pragma unroll
        for (int nt = 0; nt < 4; ++nt)
            #pragma unroll
            for (int mt = 0; mt < 4; ++mt)
                acc[mt][nt] = __builtin_amdgcn_mfma_f32_16x16x32_bf16(afr[mt][0], b0[nt], z, 0, 0, 0);
        #pragma unroll
        for (int nt = 0; nt < 4; ++nt)
            #pragma unroll
            for (int mt = 0; mt < 4; ++mt)
                acc[mt][nt] = __builtin_amdgcn_mfma_f32_16x16x32_bf16(afr[mt][1], b1[nt], acc[mt][nt], 0, 0, 0);

        // Prefetch tile t+1 into the SAME registers (b's are dead after the
        // MFMAs above); the waitcnt lands after the epilogue below.
        if (t + 1 < TPC) {
            const __hip_bfloat16* Np = Bbase + (size_t)(t + 1) * 128 * D;
            #pragma unroll
            for (int nt = 0; nt < 4; ++nt) {
                b0[nt] = *(const bf16x8*)(Np + nt * 16 * D);
                b1[nt] = *(const bf16x8*)(Np + nt * 16 * D + 32);
            }
        }

        const bool diag = (ct == bx);
        #pragma unroll
        for (int mt = 0; mt < 4; ++mt) {
            #pragma unroll
            for (int rr = 0; rr < 4; ++rr) {
                float y0 = acc[mt][0][rr], y1 = acc[mt][1][rr],
                      y2 = acc[mt][2][rr], y3 = acc[mt][3][rr];
                if (diag) {                  // acc already = base-2 logits (pre-scaled X)
                    const int dr = lrq + mt * 16 + rr - lcol;
                    if (dr == 0)  y0 = -INFINITY;
                    if (dr == 16) y1 = -INFINITY;
                    if (dr == 32) y2 = -INFINITY;
                    if (dr == 48) y3 = -INFINITY;
                }
                const int r = mt * 4 + rr;
                if (IS_USER) {
                    s_run[r] += fexp2(y0) + fexp2(y1) + fexp2(y2) + fexp2(y3);
                } else {
                    float mx   = fmaxf(fmaxf(y0, y1), fmaxf(y2, y3));
                    float newm = fmaxf(m_run[r], mx);
                    s_run[r] = s_run[r] * fexp2(m_run[r] - newm)
                             + fexp2(y0 - newm) + fexp2(y1 - newm)
                             + fexp2(y2 - newm) + fexp2(y3 - newm);
                    m_run[r] = newm;
                }
            }
        }
    }

    // Once per chunk: merge across the 16 tx lanes of THIS wave, write the
    // (row, chunk, wn) partial to its own slot.
    #pragma unroll
    for (int r = 0; r < 16; ++r) {
        float m = IS_USER ? 0.f : m_run[r];
        float s = s_run[r];
        #pragma unroll
        for (int o = 1; o < 16; o <<= 1) {
            if (IS_USER) {
                s += __shfl_xor(s, o, 64);
            } else {
                float om = __shfl_xor(m, o, 64);
                float os = __shfl_xor(s, o, 64);
                float M  = fmaxf(m, om);
                s = s * fexp2(m - M) + os * fexp2(om - M);
                m = M;
            }
        }
        if (tx == 0) {
            const int grow = r0 + wm * 64 + (r >> 2) * 16 + quad * 4 + (r & 3);
            P[(size_t)grow * NPART + chunk * 2 + wn] = make_float2(m, s);
        }
    }
}

__global__ __launch_bounds__(256, 2) void gram_lse_fused(
    const __hip_bfloat16* __restrict__ Xb0, float2* __restrict__ P0)
{
    const int branch = blockIdx.z;              // 0 = user, 1 = item
    const __hip_bfloat16* Xb = Xb0 + (size_t)branch * RPB * D;
    float2* P = P0 + (size_t)branch * RPB * NPART;
    if (branch == 0) gram_body<1>(Xb, P);
    else             gram_body<0>(Xb, P);
}

// ---------------------------------------------------------------------------
// Merge the 32 per-row partials -> lse -> reduce; fold in the positive-pair
// correction from dots[]. 128 blocks; each block covers 128 rows over 16
// iterations (each wave merges 2 rows with a 32-lane online merge).
__global__ __launch_bounds__(256) void merge_kernel(
    const float2* __restrict__ P, const float* __restrict__ dots,
    float* __restrict__ out)
{
    __shared__ float red[4];
    const int tid  = threadIdx.x;
    const int wave = tid >> 6, lane = tid & 63;

    float vsum = 0.f;
    #pragma unroll
    for (int it = 0; it < 16; ++it) {
        const int row = blockIdx.x * 128 + it * 8 + wave * 2 + (lane >> 5);
        const int c   = lane & 31;

        float2 p = P[(size_t)row * NPART + c];
        float m = p.x, s = p.y;
        #pragma unroll
        for (int o = 1; o < 32; o <<= 1) {         // online merge across 32 lanes
            float om = __shfl_xor(m, o, 64);
            float os = __shfl_xor(s, o, 64);
            float M  = fmaxf(m, om);
            s = s * fexp2(m - M) + os * fexp2(om - M);
            m = M;
        }

        if ((lane & 31) == 0)
            vsum += LN2 * (m + log2f(s)) * (1.0f / (float)RPB);   // lse_row / (2B)
    }

    // positive-pair correction: 64 dots per block
    if (tid < 64)
        vsum -= dots[blockIdx.x * 64 + tid] * (5.0f / (float)B_SZ);

    float v = vsum;
    #pragma unroll
    for (int o = 32; o > 0; o >>= 1) v += __shfl_xor(v, o, 64);
    if (lane == 0) red[wave] = v;
    __syncthreads();
    if (tid == 0)
        atomicAdd(out, red[0] + red[1] + red[2] + red[3]);
}

// ---------------------------------------------------------------------------
extern "C" void kernel_launch(void* const* d_in, const int* in_sizes, int n_in,
                              void* d_out, int out_size, void* d_ws, size_t ws_size,
                              hipStream_t stream) {
    const int*   u_idx = (const int*)d_in[0];
    const int*   i_idx = (const int*)d_in[1];
    const float* u1e   = (const float*)d_in[2];
    const float* i1e   = (const float*)d_in[3];
    const float* u2e   = (const float*)d_in[4];
    const float* i2e   = (const float*)d_in[5];
    float* out = (float*)d_out;

    __hip_bfloat16* Xbf = (__hip_bfloat16*)d_ws;                  // 2 MB
    float*  dots = (float*)((char*)d_ws + 2 * RPB * D * 2);       // 32 KB
    float2* P    = (float2*)((char*)dots + RPB * sizeof(float));  // 4 MB

    hipMemsetAsync(out, 0, sizeof(float), stream);

    gather_kernel<<<dim3(2048), dim3(256), 0, stream>>>(
        u_idx, i_idx, u1e, i1e, u2e, i2e, Xbf, dots);
    // both branches in one barrier-free launch: grid z = {user, item}
    gram_lse_fused<<<dim3(64, NCHUNK, 2), dim3(256), 0, stream>>>(Xbf, P);
    merge_kernel<<<dim3(128), dim3(256), 0, stream>>>(P, dots, out);
}

// Round 6
// 169.219 us; speedup vs baseline: 1.9218x; 1.0407x over previous
//
#include <hip/hip_runtime.h>
#include <hip/hip_bf16.h>
#include <math.h>

// Problem constants (fixed by the reference)
#define B_SZ   4096
#define D      64
#define RPB    8192                 // rows per branch = 2*B
#define NCHUNK 8                    // column chunks (blockIdx.y)
#define TPC    8                    // 128-col tiles per chunk
#define NPART  16                   // partials per row = NCHUNK * 2 (wn halves)
#define LN2    0.69314718055994531f
#define PRESCALE 2.6857914f         // sqrt(5 * log2(e)); X pre-scaled so Gram = base-2 logits

typedef __attribute__((ext_vector_type(8))) short  bf16x8;
typedef __attribute__((ext_vector_type(4))) float  f32x4;

__device__ __forceinline__ float fexp2(float x) { return __builtin_amdgcn_exp2f(x); }

// Direct global->LDS copy, 16 B per lane, zero VGPR destination cost.
typedef const __attribute__((address_space(1))) unsigned int* gptr_t;
typedef __attribute__((address_space(3))) unsigned int* lptr_t;
__device__ __forceinline__ void stage16(const void* g, void* l) {
    __builtin_amdgcn_global_load_lds((gptr_t)g, (lptr_t)l, 16, 0, 0);
}

// ws layout:
//   Xbf  : 2*8192*64 bf16  = 2 MB   (pre-scaled by PRESCALE)
//   dots : 8192 float      = 32 KB  (v1_i . v2_i, unscaled fp32)
//   P    : 16384*16 float2 = 2 MB   (per-row per-(chunk,wn) (m,s), base-2; user m=0)

// ---------------------------------------------------------------------------
__global__ __launch_bounds__(256) void gather_kernel(
    const int* __restrict__ u_idx, const int* __restrict__ i_idx,
    const float* __restrict__ u1e, const float* __restrict__ i1e,
    const float* __restrict__ u2e, const float* __restrict__ i2e,
    __hip_bfloat16* __restrict__ Xbf, float* __restrict__ dots)
{
    const int tid  = threadIdx.x;
    const int wave = tid >> 6, lane = tid & 63;
    const int g      = blockIdx.x * 4 + wave;   // 0..8191
    const int branch = g >> 12;
    const int i      = g & (B_SZ - 1);
    const int idx    = (branch == 0) ? u_idx[i] : i_idx[i];
    const float* s1  = (branch == 0) ? u1e : i1e;
    const float* s2  = (branch == 0) ? u2e : i2e;

    float v1 = s1[(size_t)idx * D + lane];
    float v2 = s2[(size_t)idx * D + lane];
    if (branch == 0) {
        float a = v1 * v1, b = v2 * v2;
        #pragma unroll
        for (int o = 32; o > 0; o >>= 1) {
            a += __shfl_xor(a, o, 64);
            b += __shfl_xor(b, o, 64);
        }
        v1 *= rsqrtf(a);
        v2 *= rsqrtf(b);
    }
    float p = v1 * v2;
    #pragma unroll
    for (int o = 32; o > 0; o >>= 1) p += __shfl_xor(p, o, 64);
    if (lane == 0) dots[g] = p;

    const size_t row1 = (size_t)branch * RPB + i;
    Xbf[row1 * D + lane]          = __float2bfloat16(v1 * PRESCALE);
    Xbf[(row1 + B_SZ) * D + lane] = __float2bfloat16(v2 * PRESCALE);
}

// ---------------------------------------------------------------------------
// MFMA Gram + per-lane online logsumexp (base-2).
// R6: B panels staged through a double-buffered 2x16KB LDS pipeline via
// global_load_lds (zero VGPR cost -> stays at the 84-reg / 3 waves-per-SIMD
// budget R2 verified). Stage for tile t+1 issues at tile t's start; the
// compiler-inserted vmcnt drain before the end-of-tile barrier lands AFTER
// the ~600-cycle exp2 epilogue, so L2 latency is fully hidden.
// XOR swizzle (byte ^= (row&7)<<4) applied on the GLOBAL SOURCE address
// (global_load_lds dest must stay linear); ds_read side reads with the same
// XOR -> fragment reads spread over all 8 bank groups (unswizzled
// row-stride-128B reads would serialize 2x).
// A fragments stay register-hoisted from global (K=64). No per-branch grid z:
// user/item interleave on blockIdx.x parity for CU load balance.
// Block: 4 waves, each owns a 64x64 C subtile (4x4 MFMA 16x16x32, K=64).
// IS_USER=1: logits bounded (|y|<=7.3) -> no max tracking, plain exp2-sum.
template<int IS_USER>
__device__ __forceinline__ void gram_body(
    const __hip_bfloat16* __restrict__ Xb, float2* __restrict__ P,
    const int bx, char* sm)
{
    const int tid   = threadIdx.x;
    const int chunk = blockIdx.y;
    const int r0    = bx * 128;

    const int wave = tid >> 6, lane = tid & 63;
    const int wm = wave >> 1, wn = wave & 1;
    const int quad = lane >> 4, tx = lane & 15;

    // Stage addressing: dest LDS byte L = wave*4096 + k*1024 + lane*16 (linear).
    // Source is swizzle-adjusted: row = L>>7, srccol = (L&127) ^ ((row&7)<<4).
    const int srow_b = wave * 32 + (lane >> 3);                  // + k*8
    const int scb    = ((lane & 7) * 16) ^ ((lane >> 3) << 4);
    const char* Xbytes = (const char*)Xb;

    // Prologue: stage tile 0 of this chunk into buffer 0.
    {
        const char* src = Xbytes + (size_t)(chunk * TPC) * 16384;
        #pragma unroll
        for (int k = 0; k < 4; ++k)
            stage16(src + (srow_b + k * 8) * 128 + scb,
                    sm + wave * 4096 + k * 1024);
    }

    // A fragments hoisted to registers, straight from global (overlaps stage).
    bf16x8 afr[4][2];
    const __hip_bfloat16* Ap = Xb + (size_t)(r0 + wm * 64 + tx) * D + quad * 8;
    #pragma unroll
    for (int mt = 0; mt < 4; ++mt)
        #pragma unroll
        for (int ks = 0; ks < 2; ++ks)
            afr[mt][ks] = *(const bf16x8*)(Ap + mt * 16 * D + ks * 32);

    float m_run[16], s_run[16];
    #pragma unroll
    for (int r = 0; r < 16; ++r) { m_run[r] = -INFINITY; s_run[r] = 0.f; }

    const int lrq  = wm * 64 + quad * 4;   // + mt*16 + rr = block-local row
    const int lcol = wn * 64 + tx;         // + nt*16      = block-local col

    // ds_read addressing (swizzled): row = wn*64 + nt*16 + tx, row&7 = tx&7.
    const int rbase = (wn * 64 + tx) * 128;          // + nt*2048
    const int key   = (tx & 7) << 4;
    const int cb0   = (quad * 16) ^ key;
    const int cb1   = (64 + quad * 16) ^ key;

    __syncthreads();   // tile 0 staged (compiler drains vmcnt before barrier)

    #pragma unroll 1
    for (int t = 0; t < TPC; ++t) {
        const int ct  = chunk * TPC + t;
        const int cur = (t & 1) << 14;

        // Stage tile t+1 into the other buffer (its reads happened before the
        // barrier that ended iteration t-1 -> WAR-safe).
        if (t + 1 < TPC) {
            const char* src = Xbytes + (size_t)(ct + 1) * 16384;
            char* dst = sm + (((t + 1) & 1) << 14) + wave * 4096;
            #pragma unroll
            for (int k = 0; k < 4; ++k)
                stage16(src + (srow_b + k * 8) * 128 + scb, dst + k * 1024);
        }

        // B fragments from LDS (swizzled addresses).
        bf16x8 b0[4], b1[4];
        #pragma unroll
        for (int nt = 0; nt < 4; ++nt) {
            b0[nt] = *(const bf16x8*)(sm + cur + rbase + nt * 2048 + cb0);
            b1[nt] = *(const bf16x8*)(sm + cur + rbase + nt * 2048 + cb1);
        }

        f32x4 acc[4][4];
        const f32x4 z = {0.f, 0.f, 0.f, 0.f};
        #pragma unroll
        for (int nt = 0; nt < 4; ++nt)
            #pragma unroll
            for (int mt = 0; mt < 4; ++mt)
                acc[mt][nt] = __builtin_amdgcn_mfma_f32_16x16x32_bf16(afr[mt][0], b0[nt], z, 0, 0, 0);
        #pragma unroll
        for (int nt = 0; nt < 4; ++nt)
            #pragma unroll
            for (int mt = 0; mt < 4; ++mt)
                acc[mt][nt] = __builtin_amdgcn_mfma_f32_16x16x32_bf16(afr[mt][1], b1[nt], acc[mt][nt], 0, 0, 0);

        const bool diag = (ct == bx);
        #pragma unroll
        for (int mt = 0; mt < 4; ++mt) {
            #pragma unroll
            for (int rr = 0; rr < 4; ++rr) {
                float y0 = acc[mt][0][rr], y1 = acc[mt][1][rr],
                      y2 = acc[mt][2][rr], y3 = acc[mt][3][rr];
                if (diag) {                  // acc already = base-2 logits (pre-scaled X)
                    const int dr = lrq + mt * 16 + rr - lcol;
                    if (dr == 0)  y0 = -INFINITY;
                    if (dr == 16) y1 = -INFINITY;
                    if (dr == 32) y2 = -INFINITY;
                    if (dr == 48) y3 = -INFINITY;
                }
                const int r = mt * 4 + rr;
                if (IS_USER) {
                    s_run[r] += fexp2(y0) + fexp2(y1) + fexp2(y2) + fexp2(y3);
                } else {
                    float mx   = fmaxf(fmaxf(y0, y1), fmaxf(y2, y3));
                    float newm = fmaxf(m_run[r], mx);
                    s_run[r] = s_run[r] * fexp2(m_run[r] - newm)
                             + fexp2(y0 - newm) + fexp2(y1 - newm)
                             + fexp2(y2 - newm) + fexp2(y3 - newm);
                    m_run[r] = newm;
                }
            }
        }

        // End-of-tile barrier: drains this wave's stage loads (compiler emits
        // vmcnt(0) before s_barrier) and aligns all waves' buffer phases.
        __syncthreads();
    }

    // Once per chunk: merge across the 16 tx lanes of THIS wave, write the
    // (row, chunk, wn) partial to its own slot.
    #pragma unroll
    for (int r = 0; r < 16; ++r) {
        float m = IS_USER ? 0.f : m_run[r];
        float s = s_run[r];
        #pragma unroll
        for (int o = 1; o < 16; o <<= 1) {
            if (IS_USER) {
                s += __shfl_xor(s, o, 64);
            } else {
                float om = __shfl_xor(m, o, 64);
                float os = __shfl_xor(s, o, 64);
                float M  = fmaxf(m, om);
                s = s * fexp2(m - M) + os * fexp2(om - M);
                m = M;
            }
        }
        if (tx == 0) {
            const int grow = r0 + wm * 64 + (r >> 2) * 16 + quad * 4 + (r & 3);
            P[(size_t)grow * NPART + chunk * 2 + wn] = make_float2(m, s);
        }
    }
}

__global__ __launch_bounds__(256, 3) void gram_lse_fused(
    const __hip_bfloat16* __restrict__ Xb0, float2* __restrict__ P0)
{
    __shared__ __align__(16) char sm[32768];     // 2 x 16KB B-panel buffers
    const int branch = blockIdx.x & 1;           // interleaved for CU balance
    const int bx     = blockIdx.x >> 1;
    const __hip_bfloat16* Xb = Xb0 + (size_t)branch * RPB * D;
    float2* P = P0 + (size_t)branch * RPB * NPART;
    if (branch == 0) gram_body<1>(Xb, P, bx, sm);
    else             gram_body<0>(Xb, P, bx, sm);
}

// ---------------------------------------------------------------------------
// Merge the 16 per-row partials -> lse -> reduce; fold in the positive-pair
// correction from dots[]. 128 blocks x 8-deep grid-stride.
__global__ __launch_bounds__(256) void merge_kernel(
    const float2* __restrict__ P, const float* __restrict__ dots,
    float* __restrict__ out)
{
    __shared__ float red[4];
    const int tid  = threadIdx.x;
    const int wave = tid >> 6, lane = tid & 63;

    float vsum = 0.f;
    #pragma unroll
    for (int k = 0; k < 8; ++k) {
        const int vb  = blockIdx.x * 8 + k;        // 0..1023
        const int gw  = vb * 4 + wave;             // 0..4095
        const int row = gw * 4 + (lane >> 4);      // 0..16383
        const int c   = lane & 15;

        float2 p = P[(size_t)row * NPART + c];
        float m = p.x, s = p.y;
        #pragma unroll
        for (int o = 1; o < 16; o <<= 1) {         // online merge across 16 lanes
            float om = __shfl_xor(m, o, 64);
            float os = __shfl_xor(s, o, 64);
            float M  = fmaxf(m, om);
            s = s * fexp2(m - M) + os * fexp2(om - M);
            m = M;
        }

        if ((lane & 15) == 0)
            vsum += LN2 * (m + log2f(s)) * (1.0f / (float)RPB);   // lse_row / (2B)
        if (tid < 8)                                              // positive-pair correction
            vsum -= dots[vb * 8 + tid] * (5.0f / (float)B_SZ);
    }

    float v = vsum;
    #pragma unroll
    for (int o = 32; o > 0; o >>= 1) v += __shfl_xor(v, o, 64);
    if (lane == 0) red[wave] = v;
    __syncthreads();
    if (tid == 0)
        atomicAdd(out, red[0] + red[1] + red[2] + red[3]);
}

// ---------------------------------------------------------------------------
extern "C" void kernel_launch(void* const* d_in, const int* in_sizes, int n_in,
                              void* d_out, int out_size, void* d_ws, size_t ws_size,
                              hipStream_t stream) {
    const int*   u_idx = (const int*)d_in[0];
    const int*   i_idx = (const int*)d_in[1];
    const float* u1e   = (const float*)d_in[2];
    const float* i1e   = (const float*)d_in[3];
    const float* u2e   = (const float*)d_in[4];
    const float* i2e   = (const float*)d_in[5];
    float* out = (float*)d_out;

    __hip_bfloat16* Xbf = (__hip_bfloat16*)d_ws;                  // 2 MB
    float*  dots = (float*)((char*)d_ws + 2 * RPB * D * 2);       // 32 KB
    float2* P    = (float2*)((char*)dots + RPB * sizeof(float));  // 2 MB

    hipMemsetAsync(out, 0, sizeof(float), stream);

    gather_kernel<<<dim3(2048), dim3(256), 0, stream>>>(
        u_idx, i_idx, u1e, i1e, u2e, i2e, Xbf, dots);
    // both branches in one launch, interleaved on blockIdx.x parity
    gram_lse_fused<<<dim3(128, NCHUNK), dim3(256), 0, stream>>>(Xbf, P);
    merge_kernel<<<dim3(128), dim3(256), 0, stream>>>(P, dots, out);
}